// Round 5
// baseline (2082.651 us; speedup 1.0000x reference)
//
#include <hip/hip_runtime.h>
#include <cstdint>
#include <cstddef>

// Problem constants
#define T_SEQ 512
#define BATCH 128
#define HID   128
#define G4    512      // 4*H
#define NCLS  10

__device__ __forceinline__ float sigmoidf_(float x) {
    return 1.f / (1.f + __expf(-x));
}
__device__ __forceinline__ float tanhf_(float x) {
    return 2.f / (1.f + __expf(-2.f * x)) - 1.f;
}

// ---------------------------------------------------------------------------
// Chunked GEMM (NT): out[m*512+n] = sum_k A[row(m)][k] * W[n][k] + bih[n]+bhh[n]
// m -> (b = m>>tcshift, tt = m&(Tc-1)); global row = b*T_SEQ + tc0 + tt;
// physical A row = rows ? rows[grow] : grow (token gather for layer 0).
// ---------------------------------------------------------------------------
#define BM 128
#define BN 128
#define BK 8

__global__ __launch_bounds__(256)
void gemm_xg(const float* __restrict__ A, const int* __restrict__ rows, int lda,
             const float* __restrict__ W, int K,
             const float* __restrict__ bih, const float* __restrict__ bhh,
             float* __restrict__ out, int tcshift, int tc0)
{
    const int ntn = G4 / BN;              // 4
    int tn = blockIdx.x % ntn;
    int tm = blockIdx.x / ntn;
    int m0 = tm * BM, n0 = tn * BN;
    int tid = threadIdx.x;

    __shared__ __align__(16) float As[BK][BM + 4];
    __shared__ __align__(16) float Ws[BK][BN + 4];

    int lr = tid >> 1;
    int lk = (tid & 1) * 4;

    const float* arow;
    {
        int m  = m0 + lr;
        int b  = m >> tcshift;
        int tt = m & ((1 << tcshift) - 1);
        int grow = b * T_SEQ + tc0 + tt;
        int r = rows ? rows[grow] : grow;
        arow = A + (size_t)r * lda;
    }
    const float* wrow = W + (size_t)(n0 + lr) * K;

    int tx = tid & 15, ty = tid >> 4;
    float acc[8][8];
#pragma unroll
    for (int i = 0; i < 8; i++)
#pragma unroll
        for (int j = 0; j < 8; j++) acc[i][j] = 0.f;

    int nch = (K + BK - 1) / BK;
    for (int ch = 0; ch < nch; ch++) {
        int k0 = ch * BK;
#pragma unroll
        for (int u = 0; u < 4; u++) {
            int k = k0 + lk + u;
            As[lk + u][lr] = (k < K) ? arow[k] : 0.f;
            Ws[lk + u][lr] = (k < K) ? wrow[k] : 0.f;
        }
        __syncthreads();
#pragma unroll
        for (int kk = 0; kk < BK; kk++) {
            float a[8], b[8];
#pragma unroll
            for (int i = 0; i < 8; i++) a[i] = As[kk][ty * 8 + i];
#pragma unroll
            for (int j = 0; j < 8; j++) b[j] = Ws[kk][tx * 8 + j];
#pragma unroll
            for (int i = 0; i < 8; i++)
#pragma unroll
                for (int j = 0; j < 8; j++) acc[i][j] += a[i] * b[j];
        }
        __syncthreads();
    }

#pragma unroll
    for (int j = 0; j < 8; j++) {
        int n = n0 + tx * 8 + j;
        float bv = bih[n] + bhh[n];
#pragma unroll
        for (int i = 0; i < 8; i++) {
            int m = m0 + ty * 8 + i;
            out[(size_t)m * G4 + n] = acc[i][j] + bv;
        }
    }
}

// ---------------------------------------------------------------------------
// LSTM recurrence, quad-interleaved gate layout.
// 512 threads/WG, one WG per (dir,b). Thread j: unit u=j>>2, gate g=j&3,
// owns w_hh row g*128+u entirely (128 weight floats in VGPRs).
//
// REGISTER RESIDENCY (the round-4 lesson): __launch_bounds__ only sets a
// MINIMUM waves/EU (a cap); the allocator still targets high occupancy and
// spilled/sank w[] (VGPR_Count=84 at round 4 -> ~512B/thread/step re-read
// from L2). amdgpu_waves_per_eu(2,2) pins occupancy to 2 waves/EU so the
// backend gets a 256-VGPR budget and keeps w[] resident (~170 needed).
// The asm memory clobber after the preload makes the weight loads
// non-rematerializable inside the step loop (loads can't move across a
// may-write-memory barrier).
//
// The 4 gates of unit u sit on 4 ADJACENT LANES of one wave: combine via
// __shfl(width=4), c replicated across the quad, no LDS gate array,
// h double-buffered -> ONE barrier per step. xg prefetched one step ahead.
// MODE 0: fused l0 fwd+rev (grid 256; dir = wg>>7), writes h0cat.
// MODE 1: single forward dir (grid 128), state only.
// ---------------------------------------------------------------------------
template <int MODE>
__global__
__attribute__((amdgpu_flat_work_group_size(512, 512)))
__attribute__((amdgpu_waves_per_eu(2, 2)))
void lstm_rec(const float* __restrict__ xg0, const float* __restrict__ xg1,
              const float* __restrict__ whh_f, const float* __restrict__ whh_r,
              float* __restrict__ hout,
              float* __restrict__ hst_f, float* __restrict__ cst_f,
              float* __restrict__ hst_r, float* __restrict__ cst_r,
              int Tc, int tc0f, int tc0r, int first)
{
    const int wg  = blockIdx.x;
    const int dir = (MODE == 0) ? (wg >> 7) : 0;
    const int b   = wg & 127;
    const float* xgb = (dir ? xg1 : xg0) + (size_t)b * Tc * G4;
    const float* whh = dir ? whh_r : whh_f;
    float* hst = dir ? hst_r : hst_f;
    float* cst = dir ? cst_r : cst_f;
    const int tc0 = dir ? tc0r : tc0f;

    const int j = threadIdx.x;   // 0..511
    const int u = j >> 2;        // hidden unit
    const int g = j & 3;         // gate: 0=i 1=f 2=g(tanh) 3=o
    const int row = g * HID + u; // row in w_hh and xg

    float w[128];
    {
        const float* wr = whh + (size_t)row * HID;
#pragma unroll
        for (int k = 0; k < 128; k += 4) {
            float4 t = *(const float4*)(wr + k);
            w[k] = t.x; w[k + 1] = t.y; w[k + 2] = t.z; w[k + 3] = t.w;
        }
    }
    // Block rematerialization of the weight loads inside the step loop:
    // a load may not be re-executed across a may-write-memory point.
    asm volatile("" ::: "memory");

    __shared__ __align__(16) float h_s[2][HID];
    float c_rep = 0.f;           // replicated across the 4 lanes of the quad
    if (j < HID) h_s[0][j] = first ? 0.f : hst[(size_t)b * HID + j];
    if (!first) c_rep = cst[(size_t)b * HID + u];
    __syncthreads();

    const float mg = (g == 2) ? 2.f : 1.f;  // tanh(a) = 2/(1+e^-2a)-1

    int buf = 0;
    float xv = xgb[(size_t)(dir ? Tc - 1 : 0) * G4 + row];
    float hlast = 0.f;

    for (int s = 0; s < Tc; s++) {
        const int tt = dir ? (Tc - 1 - s) : s;
        float nxv = 0.f;
        if (s + 1 < Tc) {
            int ttn = dir ? (tt - 1) : (tt + 1);
            nxv = xgb[(size_t)ttn * G4 + row];
        }

        // matvec over full h (wave-uniform LDS reads = broadcast, free);
        // 4 accumulator chains to stay issue-bound, not latency-bound.
        const float* hb = h_s[buf];
        float a0 = 0.f, a1 = 0.f, a2 = 0.f, a3 = 0.f;
#pragma unroll
        for (int k4 = 0; k4 < 32; k4++) {
            float4 h4 = *(const float4*)(hb + k4 * 4);
            int k = k4 * 4;
            a0 += w[k]     * h4.x;
            a1 += w[k + 1] * h4.y;
            a2 += w[k + 2] * h4.z;
            a3 += w[k + 3] * h4.w;
        }
        float a = xv + (a0 + a1) + (a2 + a3);

        // branch-free: sigmoid for g in {0,1,3}, tanh for g==2
        float e = __expf(-mg * a);
        float v = mg / (1.f + e) - (mg - 1.f);

        // quad exchange: every lane gets all four gate values
        float vi = __shfl(v, 0, 4);
        float vf = __shfl(v, 1, 4);
        float vg = __shfl(v, 2, 4);
        float vo = __shfl(v, 3, 4);

        c_rep = vf * c_rep + vi * vg;
        float th = 2.f / (1.f + __expf(-2.f * c_rep)) - 1.f;
        float hv = vo * th;
        hlast = hv;

        if (g == 0) {
            h_s[buf ^ 1][u] = hv;
            if (MODE == 0)
                hout[((size_t)b * T_SEQ + (tc0 + tt)) * 256 + dir * HID + u] = hv;
        }
        __syncthreads();
        buf ^= 1;
        xv = nxv;
    }

    if (g == 0) {
        hst[(size_t)b * HID + u] = hlast;
        cst[(size_t)b * HID + u] = c_rep;
    }
}

// ---------------------------------------------------------------------------
// Finale: layer-1 reverse LSTM's t=T-1 output is a SINGLE step from zero
// state (reverse scan processes t=T-1 first), then the FC head.
// ---------------------------------------------------------------------------
__global__ __launch_bounds__(512)
void final_k(const float* __restrict__ h0cat,
             const float* __restrict__ w_ih_r,
             const float* __restrict__ bih_r, const float* __restrict__ bhh_r,
             const float* __restrict__ h1f_last,
             const float* __restrict__ fc_w,
             const float* __restrict__ fc_b,
             float* __restrict__ out)
{
    int b = blockIdx.x;
    int j = threadIdx.x;  // 0..511
    __shared__ __align__(16) float hin[256];
    __shared__ __align__(16) float g_s[G4];
    __shared__ __align__(16) float hcat[256];

    if (j < 256) hin[j] = h0cat[((size_t)b * T_SEQ + (T_SEQ - 1)) * 256 + j];
    __syncthreads();

    float acc = bih_r[j] + bhh_r[j];
    const float* wr = w_ih_r + (size_t)j * 256;
#pragma unroll 8
    for (int k = 0; k < 256; k += 4) {
        float4 h4 = *(const float4*)&hin[k];
        float4 w4 = *(const float4*)&wr[k];
        acc += w4.x * h4.x + w4.y * h4.y + w4.z * h4.z + w4.w * h4.w;
    }
    float v = (j >= 256 && j < 384) ? tanhf_(acc) : sigmoidf_(acc);
    g_s[j] = v;
    if (j < 128) hcat[j] = h1f_last[(size_t)b * HID + j];
    __syncthreads();

    if (j < 128) {
        float gi = g_s[j], gg = g_s[j + 256], go = g_s[j + 384];
        float c = gi * gg;  // f * c0 with c0 = 0
        hcat[128 + j] = go * tanhf_(c);
    }
    __syncthreads();

    if (j < NCLS) {
        float a = fc_b[j];
        const float* fw = fc_w + (size_t)j * 256;
        for (int k = 0; k < 256; k++) a += fw[k] * hcat[k];
        out[(size_t)b * NCLS + j] = a;
    }
}

// ---------------------------------------------------------------------------
// Workspace layout:
//   [0, 64Mi)            h0cat [B][T][256]
//   [64Mi, +384Ki)       6 state slots (h,c) x {l0f, l0r, l1f}
//   [base, +2*chunk)     xgc0, xgc1 : two [B][Tc][512] chunk buffers
// Tc = largest power of two (<=256) such that both chunks fit ws_size.
// ---------------------------------------------------------------------------
extern "C" void kernel_launch(void* const* d_in, const int* in_sizes, int n_in,
                              void* d_out, int out_size, void* d_ws, size_t ws_size,
                              hipStream_t stream)
{
    (void)in_sizes; (void)n_in; (void)out_size;

    const int*   x       = (const int*)  d_in[0];
    const float* emb     = (const float*)d_in[1];
    const float* wih_l0f = (const float*)d_in[2];
    const float* whh_l0f = (const float*)d_in[3];
    const float* bih_l0f = (const float*)d_in[4];
    const float* bhh_l0f = (const float*)d_in[5];
    const float* wih_l0r = (const float*)d_in[6];
    const float* whh_l0r = (const float*)d_in[7];
    const float* bih_l0r = (const float*)d_in[8];
    const float* bhh_l0r = (const float*)d_in[9];
    const float* wih_l1f = (const float*)d_in[10];
    const float* whh_l1f = (const float*)d_in[11];
    const float* bih_l1f = (const float*)d_in[12];
    const float* bhh_l1f = (const float*)d_in[13];
    const float* wih_l1r = (const float*)d_in[14];
    const float* whh_l1r = (const float*)d_in[15];  // unused (single step, h0=c0=0)
    const float* bih_l1r = (const float*)d_in[16];
    const float* bhh_l1r = (const float*)d_in[17];
    const float* fc_w    = (const float*)d_in[18];
    const float* fc_b    = (const float*)d_in[19];
    float* out = (float*)d_out;
    (void)whh_l1r;

    char* ws = (char*)d_ws;
    float* h0cat = (float*)ws;
    float* st    = (float*)(ws + (size_t)67108864);
    float* hst0 = st + 0 * 16384;
    float* cst0 = st + 1 * 16384;
    float* hst1 = st + 2 * 16384;
    float* cst1 = st + 3 * 16384;
    float* hst2 = st + 4 * 16384;
    float* cst2 = st + 5 * 16384;
    const size_t base = (size_t)67108864 + 393216;

    // chunk buffer bytes = B*Tc*512*4 = Tc * 262144
    int Tc = 256;
    while (Tc > 32 && base + 2 * (size_t)262144 * Tc > ws_size) Tc >>= 1;
    const int NC = T_SEQ / Tc;
    int tcshift = 0;
    while ((1 << tcshift) < Tc) tcshift++;
    float* xgc0 = (float*)(ws + base);
    float* xgc1 = xgc0 + (size_t)BATCH * Tc * G4;

    const dim3 gemm_grid(Tc * (G4 / BN));  // (M/BM)*(512/BN), M = 128*Tc

    // Phase 1: layer-0 fwd+rev fused (fwd chunks ascend, rev chunks descend)
    for (int i = 0; i < NC; i++) {
        int cf = i, cr = NC - 1 - i;
        gemm_xg<<<gemm_grid, 256, 0, stream>>>(
            emb, x, 300, wih_l0f, 300, bih_l0f, bhh_l0f, xgc0, tcshift, cf * Tc);
        gemm_xg<<<gemm_grid, 256, 0, stream>>>(
            emb, x, 300, wih_l0r, 300, bih_l0r, bhh_l0r, xgc1, tcshift, cr * Tc);
        lstm_rec<0><<<dim3(2 * BATCH), 512, 0, stream>>>(
            xgc0, xgc1, whh_l0f, whh_l0r, h0cat,
            hst0, cst0, hst1, cst1, Tc, cf * Tc, cr * Tc, i == 0);
    }

    // Phase 2: layer-1 forward (state only)
    for (int i = 0; i < NC; i++) {
        gemm_xg<<<gemm_grid, 256, 0, stream>>>(
            h0cat, nullptr, 256, wih_l1f, 256, bih_l1f, bhh_l1f, xgc0, tcshift, i * Tc);
        lstm_rec<1><<<dim3(BATCH), 512, 0, stream>>>(
            xgc0, nullptr, whh_l1f, nullptr, nullptr,
            hst2, cst2, nullptr, nullptr, Tc, i * Tc, 0, i == 0);
    }

    // Phase 3: layer-1 reverse single step + FC head
    final_k<<<dim3(BATCH), 512, 0, stream>>>(
        h0cat, wih_l1r, bih_l1r, bhh_l1r, hst2, fc_w, fc_b, out);
}

// Round 7
// 1397.056 us; speedup vs baseline: 1.4907x; 1.4907x over previous
//
#include <hip/hip_runtime.h>
#include <cstdint>
#include <cstddef>

// Problem constants
#define T_SEQ 512
#define BATCH 128
#define HID   128
#define G4    512      // 4*H
#define NCLS  10

typedef unsigned short u16;
typedef unsigned int   u32;
typedef short bf16x8 __attribute__((ext_vector_type(8)));   // 8 bf16 = 4 VGPR
typedef float f32x4  __attribute__((ext_vector_type(4)));   // MFMA acc

__device__ __forceinline__ float sigmoidf_(float x) {
    return 1.f / (1.f + __expf(-x));
}
__device__ __forceinline__ float tanhf_(float x) {
    return 2.f / (1.f + __expf(-2.f * x)) - 1.f;
}

__device__ __forceinline__ u16 bf16rne(float f) {
    u32 u = __float_as_uint(f);
    u32 r = (u + 0x7fffu + ((u >> 16) & 1u)) >> 16;
    return (u16)r;
}
__device__ __forceinline__ float bf16tof(u16 s) {
    return __uint_as_float(((u32)s) << 16);
}
__device__ __forceinline__ uint4 pack8(const u16* h) {
    uint4 u;
    u.x = (u32)h[0] | ((u32)h[1] << 16);
    u.y = (u32)h[2] | ((u32)h[3] << 16);
    u.z = (u32)h[4] | ((u32)h[5] << 16);
    u.w = (u32)h[6] | ((u32)h[7] << 16);
    return u;
}

// ---------------------------------------------------------------------------
// prep_w: split the three input-projection weight matrices into bf16 hi/lo
// pairs with K zero-padded (300 -> 320 for layer 0). Runs once per launch.
// ---------------------------------------------------------------------------
__global__ __launch_bounds__(256)
void prep_w(const float* __restrict__ w0f, const float* __restrict__ w0r,
            const float* __restrict__ w1f,
            u16* __restrict__ W0f1, u16* __restrict__ W0f2,
            u16* __restrict__ W0r1, u16* __restrict__ W0r2,
            u16* __restrict__ W1f1, u16* __restrict__ W1f2)
{
    int idx = blockIdx.x * 256 + threadIdx.x;
    if (idx < 512 * 320) {
        int r = idx / 320, k = idx - r * 320;
        float v = (k < 300) ? w0f[r * 300 + k] : 0.f;
        u16 a = bf16rne(v);
        W0f1[idx] = a; W0f2[idx] = bf16rne(v - bf16tof(a));
        v = (k < 300) ? w0r[r * 300 + k] : 0.f;
        a = bf16rne(v);
        W0r1[idx] = a; W0r2[idx] = bf16rne(v - bf16tof(a));
    }
    if (idx < 512 * 256) {
        float v = w1f[idx];
        u16 a = bf16rne(v);
        W1f1[idx] = a; W1f2[idx] = bf16rne(v - bf16tof(a));
    }
}

// ---------------------------------------------------------------------------
// Split-bf16 MFMA GEMM: out[m*512+n] = A[row(m)][0:lda] . W[n][0:lda] + bias
// via C = A1*W1 + A1*W2 + A2*W1 (A2*W2 ~ 2^-18 rel, incoherent, dropped).
// A is fp32 (emb gather via rows[], or h0cat), split hi/lo bf16 on the fly in
// the staging path. W pre-split by prep_w (K padded to Kp, multiple of 32).
// Tiles: BM=BN=128, BK=32; 256 thr = 4 waves in 2x2, each wave 64x64 =
// 4x4 grid of 16x16x32 MFMA tiles. m-index of chunk-local output = b*Tc+tt.
// ---------------------------------------------------------------------------
__global__ __launch_bounds__(256)
void gemm_mfma(const float* __restrict__ A, const int* __restrict__ rows,
               int lda, int Kp,
               const u16* __restrict__ W1, const u16* __restrict__ W2,
               const float* __restrict__ bih, const float* __restrict__ bhh,
               float* __restrict__ out, int tcshift, int tc0)
{
    __shared__ __align__(16) u16 lA1[128][40];  // 40 = 32 + 8 pad (16B-aligned rows)
    __shared__ __align__(16) u16 lA2[128][40];
    __shared__ __align__(16) u16 lW1[128][40];
    __shared__ __align__(16) u16 lW2[128][40];

    const int tid = threadIdx.x;
    const int tn = blockIdx.x & 3;
    const int tm = blockIdx.x >> 2;
    const int m0 = tm * 128, n0 = tn * 128;

    const int wave = tid >> 6, lane = tid & 63;
    const int wm = wave & 1, wn = wave >> 1;
    const int quad = lane >> 4, l16 = lane & 15;

    // staging assignment: 2 threads per row, 16 k each
    const int srow = tid >> 1;
    const int sk   = (tid & 1) * 16;

    const float* arow;
    {
        int m  = m0 + srow;
        int b  = m >> tcshift;
        int tt = m & ((1 << tcshift) - 1);
        int grow = b * T_SEQ + tc0 + tt;
        int r = rows ? rows[grow] : grow;
        arow = A + (size_t)r * lda;
    }
    const u16* w1row = W1 + (size_t)(n0 + srow) * Kp + sk;
    const u16* w2row = W2 + (size_t)(n0 + srow) * Kp + sk;

    f32x4 acc[4][4];
#pragma unroll
    for (int i = 0; i < 4; i++)
#pragma unroll
        for (int j = 0; j < 4; j++) acc[i][j] = f32x4{0.f, 0.f, 0.f, 0.f};

    for (int k0 = 0; k0 < Kp; k0 += 32) {
        // --- global loads (fp32 A with bounds guard; bf16 W pre-split) ---
        float av[16];
#pragma unroll
        for (int v = 0; v < 4; v++) {
            int k = k0 + sk + v * 4;
            float4 t = {0.f, 0.f, 0.f, 0.f};
            if (k + 4 <= lda) t = *(const float4*)(arow + k);
            av[v * 4 + 0] = t.x; av[v * 4 + 1] = t.y;
            av[v * 4 + 2] = t.z; av[v * 4 + 3] = t.w;
        }
        uint4 wv1a = *(const uint4*)(w1row + k0);
        uint4 wv1b = *(const uint4*)(w1row + k0 + 8);
        uint4 wv2a = *(const uint4*)(w2row + k0);
        uint4 wv2b = *(const uint4*)(w2row + k0 + 8);

        // --- split A into hi/lo bf16 ---
        u16 h1[16], h2[16];
#pragma unroll
        for (int j = 0; j < 16; j++) {
            u16 a = bf16rne(av[j]);
            h1[j] = a;
            h2[j] = bf16rne(av[j] - bf16tof(a));
        }

        __syncthreads();   // previous chunk's fragment reads complete
        *(uint4*)&lA1[srow][sk]     = pack8(h1);
        *(uint4*)&lA1[srow][sk + 8] = pack8(h1 + 8);
        *(uint4*)&lA2[srow][sk]     = pack8(h2);
        *(uint4*)&lA2[srow][sk + 8] = pack8(h2 + 8);
        *(uint4*)&lW1[srow][sk]     = wv1a;
        *(uint4*)&lW1[srow][sk + 8] = wv1b;
        *(uint4*)&lW2[srow][sk]     = wv2a;
        *(uint4*)&lW2[srow][sk + 8] = wv2b;
        __syncthreads();

        // --- fragments: A[m=l16][k=quad*8+j], B[n=l16][k=quad*8+j] ---
        bf16x8 fa1[4], fa2[4], fw1[4], fw2[4];
#pragma unroll
        for (int t = 0; t < 4; t++) {
            int ar = wm * 64 + t * 16 + l16;
            int wr = wn * 64 + t * 16 + l16;
            fa1[t] = *(const bf16x8*)&lA1[ar][quad * 8];
            fa2[t] = *(const bf16x8*)&lA2[ar][quad * 8];
            fw1[t] = *(const bf16x8*)&lW1[wr][quad * 8];
            fw2[t] = *(const bf16x8*)&lW2[wr][quad * 8];
        }

        // --- 3 split passes, pass-major for acc independence ---
#pragma unroll
        for (int mt = 0; mt < 4; mt++)
#pragma unroll
            for (int nt = 0; nt < 4; nt++)
                acc[mt][nt] = __builtin_amdgcn_mfma_f32_16x16x32_bf16(
                    fa1[mt], fw1[nt], acc[mt][nt], 0, 0, 0);
#pragma unroll
        for (int mt = 0; mt < 4; mt++)
#pragma unroll
            for (int nt = 0; nt < 4; nt++)
                acc[mt][nt] = __builtin_amdgcn_mfma_f32_16x16x32_bf16(
                    fa1[mt], fw2[nt], acc[mt][nt], 0, 0, 0);
#pragma unroll
        for (int mt = 0; mt < 4; mt++)
#pragma unroll
            for (int nt = 0; nt < 4; nt++)
                acc[mt][nt] = __builtin_amdgcn_mfma_f32_16x16x32_bf16(
                    fa2[mt], fw1[nt], acc[mt][nt], 0, 0, 0);
    }

    // --- epilogue: D[m][n] with m = quad*4 + reg, n = l16 (verified layout) ---
#pragma unroll
    for (int nt = 0; nt < 4; nt++) {
        int n = n0 + wn * 64 + nt * 16 + l16;
        float bv = bih[n] + bhh[n];
#pragma unroll
        for (int mt = 0; mt < 4; mt++) {
            int mb = m0 + wm * 64 + mt * 16 + quad * 4;
#pragma unroll
            for (int r = 0; r < 4; r++)
                out[(size_t)(mb + r) * G4 + n] = acc[mt][nt][r] + bv;
        }
    }
}

// ---------------------------------------------------------------------------
// LSTM recurrence (round-5 proven version: fp32, absmax 0.0, 254 us).
// Quad-interleaved gate layout: 512 thr/WG, one WG per (dir,b). Thread j:
// unit u=j>>2, gate g=j&3, owns w_hh row g*128+u. h broadcast from LDS
// (wave-uniform = broadcast); gates combined via __shfl(width=4); c
// replicated in-quad; h double-buffered -> ONE barrier/step; xg prefetched.
// MODE 0: fused l0 fwd+rev (grid 256; dir=wg>>7), writes h0cat.
// MODE 1: single forward dir (grid 128), state only.
// (Known LDS-delivery wall ~2400 cyc/step; do not touch this round.)
// ---------------------------------------------------------------------------
template <int MODE>
__global__ __launch_bounds__(512, 2)
void lstm_rec(const float* __restrict__ xg0, const float* __restrict__ xg1,
              const float* __restrict__ whh_f, const float* __restrict__ whh_r,
              float* __restrict__ hout,
              float* __restrict__ hst_f, float* __restrict__ cst_f,
              float* __restrict__ hst_r, float* __restrict__ cst_r,
              int Tc, int tc0f, int tc0r, int first)
{
    const int wg  = blockIdx.x;
    const int dir = (MODE == 0) ? (wg >> 7) : 0;
    const int b   = wg & 127;
    const float* xgb = (dir ? xg1 : xg0) + (size_t)b * Tc * G4;
    const float* whh = dir ? whh_r : whh_f;
    float* hst = dir ? hst_r : hst_f;
    float* cst = dir ? cst_r : cst_f;
    const int tc0 = dir ? tc0r : tc0f;

    const int j = threadIdx.x;   // 0..511
    const int u = j >> 2;        // hidden unit
    const int g = j & 3;         // gate: 0=i 1=f 2=g(tanh) 3=o
    const int row = g * HID + u;

    float w[128];
    {
        const float* wr = whh + (size_t)row * HID;
#pragma unroll
        for (int k = 0; k < 128; k += 4) {
            float4 t = *(const float4*)(wr + k);
            w[k] = t.x; w[k + 1] = t.y; w[k + 2] = t.z; w[k + 3] = t.w;
        }
    }

    __shared__ __align__(16) float h_s[2][HID];
    float c_rep = 0.f;
    if (j < HID) h_s[0][j] = first ? 0.f : hst[(size_t)b * HID + j];
    if (!first) c_rep = cst[(size_t)b * HID + u];
    __syncthreads();

    const float mg = (g == 2) ? 2.f : 1.f;  // tanh(a) = 2/(1+e^-2a)-1

    int buf = 0;
    float xv = xgb[(size_t)(dir ? Tc - 1 : 0) * G4 + row];
    float hlast = 0.f;

    for (int s = 0; s < Tc; s++) {
        const int tt = dir ? (Tc - 1 - s) : s;
        float nxv = 0.f;
        if (s + 1 < Tc) {
            int ttn = dir ? (tt - 1) : (tt + 1);
            nxv = xgb[(size_t)ttn * G4 + row];
        }

        const float* hb = h_s[buf];
        float a0 = 0.f, a1 = 0.f, a2 = 0.f, a3 = 0.f;
#pragma unroll
        for (int k4 = 0; k4 < 32; k4++) {
            float4 h4 = *(const float4*)(hb + k4 * 4);
            int k = k4 * 4;
            a0 += w[k]     * h4.x;
            a1 += w[k + 1] * h4.y;
            a2 += w[k + 2] * h4.z;
            a3 += w[k + 3] * h4.w;
        }
        float a = xv + (a0 + a1) + (a2 + a3);

        float e = __expf(-mg * a);
        float v = mg / (1.f + e) - (mg - 1.f);

        float vi = __shfl(v, 0, 4);
        float vf = __shfl(v, 1, 4);
        float vg = __shfl(v, 2, 4);
        float vo = __shfl(v, 3, 4);

        c_rep = vf * c_rep + vi * vg;
        float th = 2.f / (1.f + __expf(-2.f * c_rep)) - 1.f;
        float hv = vo * th;
        hlast = hv;

        if (g == 0) {
            h_s[buf ^ 1][u] = hv;
            if (MODE == 0)
                hout[((size_t)b * T_SEQ + (tc0 + tt)) * 256 + dir * HID + u] = hv;
        }
        __syncthreads();
        buf ^= 1;
        xv = nxv;
    }

    if (g == 0) {
        hst[(size_t)b * HID + u] = hlast;
        cst[(size_t)b * HID + u] = c_rep;
    }
}

// ---------------------------------------------------------------------------
// Finale: layer-1 reverse LSTM's t=T-1 output is a SINGLE step from zero
// state (reverse scan processes t=T-1 first), then the FC head.
// ---------------------------------------------------------------------------
__global__ __launch_bounds__(512)
void final_k(const float* __restrict__ h0cat,
             const float* __restrict__ w_ih_r,
             const float* __restrict__ bih_r, const float* __restrict__ bhh_r,
             const float* __restrict__ h1f_last,
             const float* __restrict__ fc_w,
             const float* __restrict__ fc_b,
             float* __restrict__ out)
{
    int b = blockIdx.x;
    int j = threadIdx.x;  // 0..511
    __shared__ __align__(16) float hin[256];
    __shared__ __align__(16) float g_s[G4];
    __shared__ __align__(16) float hcat[256];

    if (j < 256) hin[j] = h0cat[((size_t)b * T_SEQ + (T_SEQ - 1)) * 256 + j];
    __syncthreads();

    float acc = bih_r[j] + bhh_r[j];
    const float* wr = w_ih_r + (size_t)j * 256;
#pragma unroll 8
    for (int k = 0; k < 256; k += 4) {
        float4 h4 = *(const float4*)&hin[k];
        float4 w4 = *(const float4*)&wr[k];
        acc += w4.x * h4.x + w4.y * h4.y + w4.z * h4.z + w4.w * h4.w;
    }
    float v = (j >= 256 && j < 384) ? tanhf_(acc) : sigmoidf_(acc);
    g_s[j] = v;
    if (j < 128) hcat[j] = h1f_last[(size_t)b * HID + j];
    __syncthreads();

    if (j < 128) {
        float gi = g_s[j], gg = g_s[j + 256], go = g_s[j + 384];
        float c = gi * gg;  // f * c0 with c0 = 0
        hcat[128 + j] = go * tanhf_(c);
    }
    __syncthreads();

    if (j < NCLS) {
        float a = fc_b[j];
        const float* fw = fc_w + (size_t)j * 256;
        for (int k = 0; k < 256; k++) a += fw[k] * hcat[k];
        out[(size_t)b * NCLS + j] = a;
    }
}

// ---------------------------------------------------------------------------
// Workspace:
//   [0, 64Mi)            h0cat [B][T][256]                        67,108,864
//   [64Mi, +384Ki)       6 state slots (h,c) x {l0f,l0r,l1f}         393,216
//   [.., +1,835,008)     W splits: W0f1/2, W0r1/2 [512][320] bf16,
//                                  W1f1/2 [512][256] bf16         1,835,008
//   [base, +2*chunk)     xgc0, xgc1 [B][Tc][512] fp32        524,288*Tc
// Tc = largest power of two (<=256) fitting ws_size.
// ---------------------------------------------------------------------------
extern "C" void kernel_launch(void* const* d_in, const int* in_sizes, int n_in,
                              void* d_out, int out_size, void* d_ws, size_t ws_size,
                              hipStream_t stream)
{
    (void)in_sizes; (void)n_in; (void)out_size;

    const int*   x       = (const int*)  d_in[0];
    const float* emb     = (const float*)d_in[1];
    const float* wih_l0f = (const float*)d_in[2];
    const float* whh_l0f = (const float*)d_in[3];
    const float* bih_l0f = (const float*)d_in[4];
    const float* bhh_l0f = (const float*)d_in[5];
    const float* wih_l0r = (const float*)d_in[6];
    const float* whh_l0r = (const float*)d_in[7];
    const float* bih_l0r = (const float*)d_in[8];
    const float* bhh_l0r = (const float*)d_in[9];
    const float* wih_l1f = (const float*)d_in[10];
    const float* whh_l1f = (const float*)d_in[11];
    const float* bih_l1f = (const float*)d_in[12];
    const float* bhh_l1f = (const float*)d_in[13];
    const float* wih_l1r = (const float*)d_in[14];
    const float* whh_l1r = (const float*)d_in[15];  // unused (single step, h0=c0=0)
    const float* bih_l1r = (const float*)d_in[16];
    const float* bhh_l1r = (const float*)d_in[17];
    const float* fc_w    = (const float*)d_in[18];
    const float* fc_b    = (const float*)d_in[19];
    float* out = (float*)d_out;
    (void)whh_l1r;

    char* ws = (char*)d_ws;
    float* h0cat = (float*)ws;
    float* st    = (float*)(ws + (size_t)67108864);
    float* hst0 = st + 0 * 16384;
    float* cst0 = st + 1 * 16384;
    float* hst1 = st + 2 * 16384;
    float* cst1 = st + 3 * 16384;
    float* hst2 = st + 4 * 16384;
    float* cst2 = st + 5 * 16384;

    u16* wsp = (u16*)(ws + (size_t)67108864 + 393216);
    u16* W0f1 = wsp;
    u16* W0f2 = wsp + 163840;
    u16* W0r1 = wsp + 327680;
    u16* W0r2 = wsp + 491520;
    u16* W1f1 = wsp + 655360;
    u16* W1f2 = wsp + 786432;

    const size_t base = (size_t)67108864 + 393216 + 1835008;

    int Tc = 256;
    while (Tc > 32 && base + 2 * (size_t)262144 * Tc > ws_size) Tc >>= 1;
    const int NC = T_SEQ / Tc;
    int tcshift = 0;
    while ((1 << tcshift) < Tc) tcshift++;
    float* xgc0 = (float*)(ws + base);
    float* xgc1 = xgc0 + (size_t)BATCH * Tc * G4;

    const dim3 gemm_grid(Tc * 4);  // (128*Tc/128) M-tiles x 4 N-tiles

    // Weight splits (once per launch)
    prep_w<<<dim3(640), 256, 0, stream>>>(
        wih_l0f, wih_l0r, wih_l1f, W0f1, W0f2, W0r1, W0r2, W1f1, W1f2);

    // Phase 1: layer-0 fwd+rev fused (fwd chunks ascend, rev chunks descend)
    for (int i = 0; i < NC; i++) {
        int cf = i, cr = NC - 1 - i;
        gemm_mfma<<<gemm_grid, 256, 0, stream>>>(
            emb, x, 300, 320, W0f1, W0f2, bih_l0f, bhh_l0f,
            xgc0, tcshift, cf * Tc);
        gemm_mfma<<<gemm_grid, 256, 0, stream>>>(
            emb, x, 300, 320, W0r1, W0r2, bih_l0r, bhh_l0r,
            xgc1, tcshift, cr * Tc);
        lstm_rec<0><<<dim3(2 * BATCH), 512, 0, stream>>>(
            xgc0, xgc1, whh_l0f, whh_l0r, h0cat,
            hst0, cst0, hst1, cst1, Tc, cf * Tc, cr * Tc, i == 0);
    }

    // Phase 2: layer-1 forward (state only)
    for (int i = 0; i < NC; i++) {
        gemm_mfma<<<gemm_grid, 256, 0, stream>>>(
            h0cat, nullptr, 256, 256, W1f1, W1f2, bih_l1f, bhh_l1f,
            xgc0, tcshift, i * Tc);
        lstm_rec<1><<<dim3(BATCH), 512, 0, stream>>>(
            xgc0, nullptr, whh_l1f, nullptr, nullptr,
            hst2, cst2, nullptr, nullptr, Tc, i * Tc, 0, i == 0);
    }

    // Phase 3: layer-1 reverse single step + FC head
    final_k<<<dim3(BATCH), 512, 0, stream>>>(
        h0cat, wih_l1r, bih_l1r, bhh_l1r, hst2, fc_w, fc_b, out);
}